// Round 13
// baseline (198.581 us; speedup 1.0000x reference)
//
#include <hip/hip_runtime.h>

#define B_  64
#define C_  32
#define N_  1152
#define DI_ 8
#define DC_ 16
#define NCH 3                // n's per staged chunk
#define NSLOT 128            // chunk-slots; slot handles chunks slot, +128, +256
#define STH 512              // 8 waves

// ---------------- caps_pass: one routing pass, hat recomputed --------------
// R12 post-mortem: materialized-hat architecture is the wall (75.5 MB x 4
// trips at ~2.5 TB/s effective, insensitive to all latency tricks). This
// kernel recomputes hat from LDS-staged W each pass with the two prior
// recompute diseases fixed: bq=4 (halves LDS frag reads vs R5's 43us) and
// NO stores inside the barrier loop (R8/R10's 92 MB barrier-chopped stores
// ran at 2 TB/s) — only the 16.8 MB p1 slab at kernel end. W/X for chunk
// cc+1 are prefetched into VGPRs during cc's compute (1 block/CU has no
// cross-block overlap). grid 256 = bg(2) x slot(128), 1 block/CU.
__global__ __launch_bounds__(STH, 2) void caps_pass(
    const float* __restrict__ X, const float* __restrict__ W,
    const float* __restrict__ accb, float* __restrict__ p1, int t)
{
    __shared__ float wlds[NCH * 64 * 64];    // [nl][f=2c+h][phys quad q^(c&7)]
    __shared__ float xlds[NCH * 32 * 8];     // [nl][b_local 32][8]

    const int bg   = blockIdx.x & 1;
    const int slot = blockIdx.x >> 1;
    const int tid  = threadIdx.x;
    const int w    = tid >> 6;
    const int lane = tid & 63;
    const int c    = lane & 31;
    const int h    = lane >> 5;
    const int bl0  = w * 4;                  // wave's 4 local b's
    const int le   = 2 * c + h;
    const int sw   = c & 7;

    float areg[4][8];
    if (t > 0) {
#pragma unroll
        for (int bq = 0; bq < 4; bq++) {
            const float* ap = accb + (size_t)(bg * 32 + bl0 + bq) * 512 + le * 8;
            const float4 a0 = *(const float4*)ap;
            const float4 a1 = *(const float4*)(ap + 4);
            areg[bq][0]=a0.x; areg[bq][1]=a0.y; areg[bq][2]=a0.z; areg[bq][3]=a0.w;
            areg[bq][4]=a1.x; areg[bq][5]=a1.y; areg[bq][6]=a1.z; areg[bq][7]=a1.w;
        }
    }

    float acc[4][8];
#pragma unroll
    for (int bq = 0; bq < 4; bq++)
#pragma unroll
        for (int r = 0; r < 8; r++) acc[bq][r] = 0.f;

    // prefetch registers: 3072 W-granules / 512 thr = 6 float4; X: 192 thr x 1
    float4 wpre[6];
    float4 xpre = make_float4(0.f, 0.f, 0.f, 0.f);
    {
        const int n0 = slot * NCH;
#pragma unroll
        for (int k = 0; k < 6; k++) {
            const int G = tid + k * STH;
            const int nl = G >> 10, f = (G >> 4) & 63, q = G & 15;
            const int wc = f >> 1, wh = f & 1;
            wpre[k] = *(const float4*)(W + (size_t)(wc * N_ + n0 + nl) * 128 + wh * 64 + q * 4);
        }
        if (tid < NCH * 64) {
            const int nl = tid >> 6, bl = (tid >> 1) & 31, qx = tid & 1;
            xpre = *(const float4*)(X + (size_t)((bg * 32 + bl) * N_ + n0 + nl) * DI_ + qx * 4);
        }
    }

    for (int cc = 0; cc < 3; cc++) {
        if (cc) __syncthreads();             // readers of previous chunk done
        // commit prefetched chunk to LDS (XOR quad swizzle: conflict-free reads)
#pragma unroll
        for (int k = 0; k < 6; k++) {
            const int G = tid + k * STH;
            const int nl = G >> 10, f = (G >> 4) & 63, q = G & 15;
            const int wc = f >> 1;
            *(float4*)(wlds + (nl * 64 + f) * 64 + (q ^ (wc & 7)) * 4) = wpre[k];
        }
        if (tid < NCH * 64) {
            const int nl = tid >> 6, bl = (tid >> 1) & 31, qx = tid & 1;
            *(float4*)(xlds + (nl * 32 + bl) * 8 + qx * 4) = xpre;
        }
        __syncthreads();
        // issue next chunk's global loads — in flight during compute below
        if (cc < 2) {
            const int n0 = (slot + (cc + 1) * NSLOT) * NCH;
#pragma unroll
            for (int k = 0; k < 6; k++) {
                const int G = tid + k * STH;
                const int nl = G >> 10, f = (G >> 4) & 63, q = G & 15;
                const int wc = f >> 1, wh = f & 1;
                wpre[k] = *(const float4*)(W + (size_t)(wc * N_ + n0 + nl) * 128 + wh * 64 + q * 4);
            }
            if (tid < NCH * 64) {
                const int nl = tid >> 6, bl = (tid >> 1) & 31, qx = tid & 1;
                xpre = *(const float4*)(X + (size_t)((bg * 32 + bl) * N_ + n0 + nl) * DI_ + qx * 4);
            }
        }

#pragma unroll
        for (int nl = 0; nl < NCH; nl++) {
            float4 xa[4], xb[4];
#pragma unroll
            for (int bq = 0; bq < 4; bq++) {
                const float* xp = xlds + (nl * 32 + bl0 + bq) * 8;   // broadcast
                xa[bq] = *(const float4*)xp;
                xb[bq] = *(const float4*)(xp + 4);
            }
            float hat[4][8];
            const float* frag = wlds + (nl * 64 + le) * 64;
#pragma unroll
            for (int r = 0; r < 8; r++) {
                const int pa = ((2 * r) ^ sw) * 4;
                const int pb = pa ^ 4;
                const float4 wa = *(const float4*)(frag + pa);
                const float4 wb = *(const float4*)(frag + pb);
#pragma unroll
                for (int bq = 0; bq < 4; bq++) {
                    hat[bq][r] = wa.x*xa[bq].x + wa.y*xa[bq].y + wa.z*xa[bq].z + wa.w*xa[bq].w
                               + wb.x*xb[bq].x + wb.y*xb[bq].y + wb.z*xb[bq].z + wb.w*xb[bq].w;
                }
            }
#pragma unroll
            for (int bq = 0; bq < 4; bq++) {
                if (t > 0) {
                    float lg = hat[bq][0]*areg[bq][0] + hat[bq][1]*areg[bq][1]
                             + hat[bq][2]*areg[bq][2] + hat[bq][3]*areg[bq][3]
                             + hat[bq][4]*areg[bq][4] + hat[bq][5]*areg[bq][5]
                             + hat[bq][6]*areg[bq][6] + hat[bq][7]*areg[bq][7];
                    lg += __shfl_xor(lg, 32, 64);    // combine i-halves (same c)
                    const float e = __expf(lg);      // no max-subtract: |lg| small
                    float s = e;
#pragma unroll
                    for (int m = 16; m >= 1; m >>= 1) s += __shfl_xor(s, m, 64);
                    const float sc = e * __builtin_amdgcn_rcpf(s);
#pragma unroll
                    for (int r = 0; r < 8; r++) acc[bq][r] += sc * hat[bq][r];
                } else {
#pragma unroll
                    for (int r = 0; r < 8; r++) acc[bq][r] += hat[bq][r];  // softc=1/32 folded below
                }
            }
        }
    }

    // single store region at kernel end — stores never gated by the cc barriers
    const float f0 = (t == 0) ? 0.03125f : 1.0f;
    float* pout = p1 + (size_t)(bg * NSLOT + slot) * 16384;
#pragma unroll
    for (int bq = 0; bq < 4; bq++) {
        float* pb = pout + (bl0 + bq) * 512 + le * 8;
        *(float4*)pb       = make_float4(acc[bq][0]*f0, acc[bq][1]*f0, acc[bq][2]*f0, acc[bq][3]*f0);
        *(float4*)(pb + 4) = make_float4(acc[bq][4]*f0, acc[bq][5]*f0, acc[bq][6]*f0, acc[bq][7]*f0);
    }
}

// ---------------- caps_r1: reduce the 128 slot-slabs, squash ---------------
// (verified R8 kernel; p1 layout [bg2][slot128][32 b][512 e])
__global__ __launch_bounds__(256) void caps_r1(
    const float* __restrict__ p1, float* __restrict__ accb,
    float* __restrict__ out, int t)
{
    const int b   = blockIdx.x >> 2;
    const int q   = blockIdx.x & 3;
    const int tid = threadIdx.x;
    const int e   = q * 128 + (tid >> 1);
    const int p   = tid & 1;
    const int bg  = b >> 5, bl = b & 31;
    const float* base = p1 + (size_t)bg * NSLOT * 16384 + (size_t)bl * 512 + e;
    float v = 0.f;
#pragma unroll 8
    for (int ch = p; ch < NSLOT; ch += 2)
        v += base[(size_t)ch * 16384];
    v += __shfl_xor(v, 1, 64);
    float sq = v * v;
#pragma unroll
    for (int m = 2; m <= 16; m <<= 1) sq += __shfl_xor(sq, m, 64);  // sum over i
    const float scale = sq / (1.f + sq) * rsqrtf(sq + 1e-7f);
    const float ov = v * scale;
    if (p == 0) {
        const int oidx = b * 512 + e;
        if (t == 2) out[oidx] = ov;
        else        accb[oidx] = (t == 0) ? ov : (accb[oidx] + ov);
    }
}

extern "C" void kernel_launch(void* const* d_in, const int* in_sizes, int n_in,
                              void* d_out, int out_size, void* d_ws, size_t ws_size,
                              hipStream_t stream) {
    const float* X = (const float*)d_in[0];   // [B,N,DI]
    const float* W = (const float*)d_in[1];   // [C,N,DC,DI]
    float* out = (float*)d_out;               // [B,C,DC]

    float* p1   = (float*)d_ws;                         // 256 slabs x 64 KB = 16.8 MB
    float* accb = p1 + (size_t)256 * 16384;             // 128 KB

    for (int t = 0; t < 3; t++) {
        caps_pass<<<256, STH, 0, stream>>>(X, W, accb, p1, t);
        caps_r1  <<<256, 256, 0, stream>>>(p1, accb, out, t);
    }
}